// Round 2
// baseline (759.341 us; speedup 1.0000x reference)
//
#include <hip/hip_runtime.h>

// Product quantizer: N=16384, D=1024, M=64 subspaces, K=256 codes, d=16.
// Main pass: split-bf16 MFMA scores s = x·c - 0.5||c||^2 (argmax == argmin dist).
//   x = xh + xl, c = ch + cl (bf16 splits); s ~= xh·ch + xl·ch + xh·cl  (err ~1e-4).
// Track best + second-best; gap < MARGIN -> flag -> f64 refine kernel re-decides.

#define DIMS   1024
#define MSUB   64
#define KCODE  256
#define DSUB   16

static constexpr float MARGIN = 0.05f;

typedef __attribute__((ext_vector_type(4))) short s16x4;
typedef __attribute__((ext_vector_type(4))) float f32x4;

static __device__ __forceinline__ short f2bf(float f) {
    unsigned u = __float_as_uint(f);
    u += 0x7fffu + ((u >> 16) & 1u);          // RNE to bf16
    return (short)(u >> 16);
}
static __device__ __forceinline__ float bf2f(short h) {
    return __uint_as_float(((unsigned)(unsigned short)h) << 16);
}

static __device__ __forceinline__ f32x4 mfma16(s16x4 a, s16x4 b, f32x4 c) {
#if __has_builtin(__builtin_amdgcn_mfma_f32_16x16x16bf16_1k)
    return __builtin_amdgcn_mfma_f32_16x16x16bf16_1k(a, b, c, 0, 0, 0);
#else
    asm("v_mfma_f32_16x16x16_bf16 %0, %1, %2, %0" : "+v"(c) : "v"(a), "v"(b));
    return c;
#endif
}

// Block = 512 threads = 8 waves. Wave w handles m = (blockIdx&7)*8 + w for 256 rows.
// Per wave: B frags (16 k-tiles, hi+lo) in 64 VGPRs; -0.5||c||^2 in LDS (1KB/wave).
// MFMA 16x16x16: A row = lane&15, k = (lane>>4)*4+j ; B col = lane&15, k = (lane>>4)*4+j ;
// C/D col = lane&15, row = (lane>>4)*4+reg.
__global__ __launch_bounds__(512, 4) void pq_main(
    const float* __restrict__ embeds,
    const float* __restrict__ codebooks,
    float* __restrict__ out,
    unsigned* __restrict__ flag_cnt,
    unsigned* __restrict__ flag_list,
    unsigned flag_cap)
{
    __shared__ float hn_lds[8][KCODE];   // [wave][code]: -0.5*||c||^2

    const int tid  = threadIdx.x;
    const int w    = tid >> 6;
    const int l    = tid & 63;
    const int col  = l & 15;      // MFMA column (code within tile) / d-element for writes
    const int dseg = l >> 4;      // k-segment for A/B frags; row-group for C
    const int m    = ((blockIdx.x & 7) << 3) + w;
    const int nblk = (blockIdx.x >> 3) << 8;   // 256 rows per block

    const float* cbm = codebooks + (size_t)m * (KCODE * DSUB);

    // ---- Setup: B fragments (bf16 hi/lo) + code norms ----
    s16x4 bhi[16], blo[16];
    #pragma unroll
    for (int kt = 0; kt < 16; ++kt) {
        const float4 cv = *(const float4*)(cbm + (kt * 16 + col) * DSUB + dseg * 4);
        short h0 = f2bf(cv.x), h1 = f2bf(cv.y), h2 = f2bf(cv.z), h3 = f2bf(cv.w);
        bhi[kt] = (s16x4){h0, h1, h2, h3};
        blo[kt] = (s16x4){f2bf(cv.x - bf2f(h0)), f2bf(cv.y - bf2f(h1)),
                          f2bf(cv.z - bf2f(h2)), f2bf(cv.w - bf2f(h3))};
        float p = fmaf(cv.x, cv.x, fmaf(cv.y, cv.y, fmaf(cv.z, cv.z, cv.w * cv.w)));
        p += __shfl_xor(p, 16);
        p += __shfl_xor(p, 32);
        if (dseg == 0) hn_lds[w][kt * 16 + col] = -0.5f * p;
    }
    __syncthreads();

    // ---- Main loop over 16 n-tiles of 16 rows ----
    const float* xp = embeds + (size_t)(nblk + col) * DIMS + m * DSUB + dseg * 4;
    float4 xv = *(const float4*)xp;

    #pragma unroll 1
    for (int t = 0; t < 16; ++t) {
        s16x4 ah, al;
        {
            short h0 = f2bf(xv.x), h1 = f2bf(xv.y), h2 = f2bf(xv.z), h3 = f2bf(xv.w);
            ah = (s16x4){h0, h1, h2, h3};
            al = (s16x4){f2bf(xv.x - bf2f(h0)), f2bf(xv.y - bf2f(h1)),
                         f2bf(xv.z - bf2f(h2)), f2bf(xv.w - bf2f(h3))};
        }
        if (t < 15) xv = *(const float4*)(xp + (size_t)(t + 1) * 16 * DIMS);

        float best[4] = {-3e38f, -3e38f, -3e38f, -3e38f};
        float sec[4]  = {-3e38f, -3e38f, -3e38f, -3e38f};
        int   idx[4]  = {0, 0, 0, 0};

        #pragma unroll
        for (int kt = 0; kt < 16; ++kt) {
            const float nh = hn_lds[w][kt * 16 + col];
            f32x4 acc = {nh, nh, nh, nh};
            acc = mfma16(ah, bhi[kt], acc);
            acc = mfma16(al, bhi[kt], acc);
            acc = mfma16(ah, blo[kt], acc);
            const int code = kt * 16 + col;
            #pragma unroll
            for (int j = 0; j < 4; ++j) {
                float s = acc[j];
                bool gt = s > best[j];
                idx[j]  = gt ? code : idx[j];
                sec[j]  = fmaxf(sec[j], fminf(s, best[j]));  // 2nd-best update (old best)
                best[j] = fmaxf(best[j], s);
            }
        }

        // Butterfly reduce across the 16 lanes sharing this row group.
        #pragma unroll
        for (int j = 0; j < 4; ++j) {
            #pragma unroll
            for (int msk = 1; msk <= 8; msk <<= 1) {
                float ob = __shfl_xor(best[j], msk);
                float os = __shfl_xor(sec[j],  msk);
                int   oi = __shfl_xor(idx[j],  msk);
                float mn = fminf(best[j], ob);
                sec[j]   = fmaxf(fmaxf(sec[j], os), mn);     // 2nd of union = max3
                bool gt  = ob > best[j];
                idx[j]   = gt ? oi : idx[j];
                best[j]  = fmaxf(best[j], ob);
            }
        }
        // Now all 16 lanes of group `dseg` hold identical results for rows dseg*4+j.

        const int n0 = nblk + t * 16;
        #pragma unroll
        for (int j = 0; j < 4; ++j) {
            const int r = dseg * 4 + j;
            float cval = cbm[idx[j] * DSUB + col];           // gather from L2-hot codebook
            out[(size_t)(n0 + r) * DIMS + m * DSUB + col] = cval;
        }
        if (col == 0) {
            #pragma unroll
            for (int j = 0; j < 4; ++j) {
                if (best[j] - sec[j] < MARGIN) {
                    unsigned p = atomicAdd(flag_cnt, 1u);
                    if (p < flag_cap) {
                        const int r = dseg * 4 + j;
                        flag_list[p] = (unsigned)((n0 + r) * 64 + m);
                    }
                }
            }
        }
    }
}

// One wave per flagged (n,m): exact f64 distances, strict-< ascending k (first-min wins).
__global__ __launch_bounds__(256) void pq_refine(
    const float* __restrict__ embeds,
    const float* __restrict__ codebooks,
    float* __restrict__ out,
    const unsigned* __restrict__ flag_cnt,
    const unsigned* __restrict__ flag_list,
    unsigned flag_cap)
{
    unsigned cnt = *flag_cnt;
    if (cnt > flag_cap) cnt = flag_cap;
    const int l = threadIdx.x & 63;
    const unsigned wid = (blockIdx.x << 2) | (unsigned)(threadIdx.x >> 6);
    const unsigned nw  = gridDim.x << 2;

    for (unsigned i = wid; i < cnt; i += nw) {
        const unsigned e = flag_list[i];
        const int n = (int)(e >> 6), m = (int)(e & 63u);
        const float* xrow = embeds + (size_t)n * DIMS + m * DSUB;
        double xd[DSUB];
        #pragma unroll
        for (int dd = 0; dd < DSUB; ++dd) xd[dd] = (double)xrow[dd];
        const float* cbm = codebooks + (size_t)m * (KCODE * DSUB);

        double bd = 1e300;
        int bi = 0;
        #pragma unroll 1
        for (int cc = 0; cc < 4; ++cc) {
            const int c = l * 4 + cc;                 // lane-local ascending order
            const float* cp = cbm + c * DSUB;
            double s = 0.0;
            #pragma unroll
            for (int dd = 0; dd < DSUB; ++dd) {
                double diff = xd[dd] - (double)cp[dd];
                s = fma(diff, diff, s);
            }
            if (s < bd) { bd = s; bi = c; }
        }
        #pragma unroll
        for (int msk = 1; msk <= 32; msk <<= 1) {
            double ob = __shfl_xor(bd, msk);
            int   oi  = __shfl_xor(bi, msk);
            if (ob < bd || (ob == bd && oi < bi)) { bd = ob; bi = oi; }
        }
        if (l < DSUB) out[(size_t)n * DIMS + m * DSUB + l] = cbm[bi * DSUB + l];
    }
}

extern "C" void kernel_launch(void* const* d_in, const int* in_sizes, int n_in,
                              void* d_out, int out_size, void* d_ws, size_t ws_size,
                              hipStream_t stream)
{
    const float* embeds    = (const float*)d_in[0];
    const float* codebooks = (const float*)d_in[1];
    float* out = (float*)d_out;

    unsigned* flag_cnt  = (unsigned*)d_ws;
    unsigned* flag_list = (unsigned*)d_ws + 4;   // 16B offset
    unsigned flag_cap = 0;
    if (ws_size >= 32) {
        size_t cap = (ws_size - 16) / sizeof(unsigned);
        flag_cap = (cap > 0x7FFFFFFFull) ? 0x7FFFFFFFu : (unsigned)cap;
    }

    hipMemsetAsync(d_ws, 0, 16, stream);

    // 8 m-groups x 64 n-chunks of 256 rows
    pq_main<<<dim3(512), dim3(512), 0, stream>>>(
        embeds, codebooks, out, flag_cnt, flag_list, flag_cap);

    pq_refine<<<dim3(512), dim3(256), 0, stream>>>(
        embeds, codebooks, out, flag_cnt, flag_list, flag_cap);
}

// Round 3
// 406.444 us; speedup vs baseline: 1.8683x; 1.8683x over previous
//
#include <hip/hip_runtime.h>

// Product quantizer: N=16384, D=1024, M=64 subspaces, K=256 codes, d=16.
// Scores s = x·c - 0.5||c||^2 via split-bf16 MFMA (3 products: ch·xh + cl·xh + ch·xl),
// error < ~1e-3. A = codebook (from LDS), B = x (4 VGPRs). C gives each lane 4 codes of
// one embed-row -> scalar best/sec/idx tracking, 2-round cross-lane reduce.
// gap < MARGIN -> flag -> exact f64 refine kernel re-decides (first-min tie-break).

#define DIMS   1024
#define MSUB   64
#define KCODE  256
#define DSUB   16

static constexpr float MARGIN = 0.03f;

typedef __attribute__((ext_vector_type(4))) short s16x4;
typedef __attribute__((ext_vector_type(4))) float f32x4;

static __device__ __forceinline__ short f2bf(float f) {
    unsigned u = __float_as_uint(f);
    u += 0x7fffu + ((u >> 16) & 1u);          // RNE to bf16
    return (short)(u >> 16);
}
static __device__ __forceinline__ float bf2f(short h) {
    return __uint_as_float(((unsigned)(unsigned short)h) << 16);
}

static __device__ __forceinline__ f32x4 mfma16(s16x4 a, s16x4 b, f32x4 c) {
#if __has_builtin(__builtin_amdgcn_mfma_f32_16x16x16bf16_1k)
    return __builtin_amdgcn_mfma_f32_16x16x16bf16_1k(a, b, c, 0, 0, 0);
#else
    asm("v_mfma_f32_16x16x16_bf16 %0, %1, %2, %0" : "+v"(c) : "v"(a), "v"(b));
    return c;
#endif
}

// Block = 256 threads = 4 waves, all on one m; block covers 1024 rows (wave: 256 rows,
// 16 tiles of 16 rows). Grid = 64 m x 16 row-groups = 1024 blocks (4/CU, no tail).
__global__ __launch_bounds__(256, 4) void pq_main(
    const float* __restrict__ embeds,
    const float* __restrict__ codebooks,
    float* __restrict__ out,
    unsigned* __restrict__ flag_cnt,
    unsigned* __restrict__ flag_list,
    unsigned flag_cap)
{
    __shared__ short chi[KCODE * DSUB];   // 8KB: bf16 hi of codebook[m]
    __shared__ short clo[KCODE * DSUB];   // 8KB: bf16 lo residual
    __shared__ float cnorm[KCODE];        // 1KB: -0.5*||c||^2

    const int tid = threadIdx.x;
    const int m   = blockIdx.x & 63;
    const int g   = blockIdx.x >> 6;
    const float* cbm = codebooks + (size_t)m * (KCODE * DSUB);

    // ---- Stage codebook[m]: thread tid owns code tid (64B coalesced loads) ----
    {
        const float4* src = (const float4*)(cbm + tid * DSUB);
        float c[16];
        #pragma unroll
        for (int q = 0; q < 4; ++q) {
            float4 v = src[q];
            c[4*q+0] = v.x; c[4*q+1] = v.y; c[4*q+2] = v.z; c[4*q+3] = v.w;
        }
        float ss = 0.f;
        s16x4* chv = (s16x4*)chi + tid * 4;
        s16x4* clv = (s16x4*)clo + tid * 4;
        #pragma unroll
        for (int q = 0; q < 4; ++q) {
            short h0 = f2bf(c[4*q+0]), h1 = f2bf(c[4*q+1]);
            short h2 = f2bf(c[4*q+2]), h3 = f2bf(c[4*q+3]);
            chv[q] = (s16x4){h0, h1, h2, h3};
            clv[q] = (s16x4){f2bf(c[4*q+0] - bf2f(h0)), f2bf(c[4*q+1] - bf2f(h1)),
                             f2bf(c[4*q+2] - bf2f(h2)), f2bf(c[4*q+3] - bf2f(h3))};
            ss = fmaf(c[4*q+0], c[4*q+0], ss); ss = fmaf(c[4*q+1], c[4*q+1], ss);
            ss = fmaf(c[4*q+2], c[4*q+2], ss); ss = fmaf(c[4*q+3], c[4*q+3], ss);
        }
        cnorm[tid] = -0.5f * ss;
    }
    __syncthreads();

    const int w   = tid >> 6;
    const int l   = tid & 63;
    const int col = l & 15;       // embed-row within 16-row tile (MFMA B col / C col)
    const int ds  = l >> 4;       // k-segment (dims ds*4..+4) and C row-group (codes)
    const int n0  = (g << 10) + (w << 8);

    const float* xp = embeds + (size_t)(n0 + col) * DIMS + m * DSUB + ds * 4;
    float*       op = out    + (size_t)(n0 + col) * DIMS + m * DSUB + ds * 4;
    const s16x4* chv = (const s16x4*)chi + col * 4 + ds;   // + kt*64 per k-tile
    const s16x4* clv = (const s16x4*)clo + col * 4 + ds;
    const f32x4* hv  = (const f32x4*)cnorm + ds;           // + kt*4 per k-tile
    const int cb4 = ds * 4;

    float4 xv = *(const float4*)xp;

    #pragma unroll 1
    for (int t = 0; t < 16; ++t) {
        // B fragments: x hi/lo (4 dims of row n0+t*16+col)
        s16x4 bh, bl;
        {
            short h0 = f2bf(xv.x), h1 = f2bf(xv.y), h2 = f2bf(xv.z), h3 = f2bf(xv.w);
            bh = (s16x4){h0, h1, h2, h3};
            bl = (s16x4){f2bf(xv.x - bf2f(h0)), f2bf(xv.y - bf2f(h1)),
                         f2bf(xv.z - bf2f(h2)), f2bf(xv.w - bf2f(h3))};
        }
        if (t < 15) xv = *(const float4*)(xp + (size_t)(t + 1) * 16 * DIMS);

        float best = -3e38f, sec = -3e38f;
        int idx = 0;

        #pragma unroll
        for (int kt = 0; kt < 16; ++kt) {
            f32x4 acc = hv[kt * 4];            // init = -0.5||c||^2 (4 codes)
            s16x4 ah = chv[kt * 64];           // codebook hi frag (codes kt*16+col row)
            s16x4 al = clv[kt * 64];
            acc = mfma16(ah, bh, acc);         // ch·xh
            acc = mfma16(al, bh, acc);         // cl·xh
            acc = mfma16(ah, bl, acc);         // ch·xl
            #pragma unroll
            for (int r = 0; r < 4; ++r) {
                float s = acc[r];
                bool gt = s > best;
                idx  = gt ? (cb4 | (kt * 16 + r)) : idx;
                sec  = fmaxf(sec, fminf(s, best));
                best = fmaxf(best, s);
            }
        }

        // Reduce the 4 code-partitions (lanes xor 16, 32) -> all lanes of col agree.
        #pragma unroll
        for (int msk = 16; msk <= 32; msk <<= 1) {
            float ob = __shfl_xor(best, msk);
            float os = __shfl_xor(sec,  msk);
            int   oi = __shfl_xor(idx,  msk);
            sec  = fmaxf(fmaxf(sec, os), fminf(best, ob));
            bool gt = ob > best;
            idx  = gt ? oi : idx;
            best = fmaxf(best, ob);
        }

        // Epilogue: exact f32 codeword gather (L1-hot) + coalesced 64B/row store.
        const float4 cv = *(const float4*)(cbm + (size_t)idx * DSUB + cb4);
        *(float4*)(op + (size_t)t * 16 * DIMS) = cv;

        if (ds == 0 && best - sec < MARGIN) {
            unsigned p = atomicAdd(flag_cnt, 1u);
            if (p < flag_cap)
                flag_list[p] = (unsigned)((n0 + t * 16 + col) * 64 + m);
        }
    }
}

// One wave per flagged (n,m): exact f64 distances, first-min tie-break.
__global__ __launch_bounds__(256) void pq_refine(
    const float* __restrict__ embeds,
    const float* __restrict__ codebooks,
    float* __restrict__ out,
    const unsigned* __restrict__ flag_cnt,
    const unsigned* __restrict__ flag_list,
    unsigned flag_cap)
{
    unsigned cnt = *flag_cnt;
    if (cnt > flag_cap) cnt = flag_cap;
    const int l = threadIdx.x & 63;
    const unsigned wid = (blockIdx.x << 2) | (unsigned)(threadIdx.x >> 6);
    const unsigned nw  = gridDim.x << 2;

    for (unsigned i = wid; i < cnt; i += nw) {
        const unsigned e = flag_list[i];
        const int n = (int)(e >> 6), m = (int)(e & 63u);
        const float* xrow = embeds + (size_t)n * DIMS + m * DSUB;
        double xd[DSUB];
        #pragma unroll
        for (int dd = 0; dd < DSUB; ++dd) xd[dd] = (double)xrow[dd];
        const float* cbm = codebooks + (size_t)m * (KCODE * DSUB);

        double bd = 1e300;
        int bi = 0;
        #pragma unroll 1
        for (int cc = 0; cc < 4; ++cc) {
            const int c = l * 4 + cc;
            const float* cp = cbm + c * DSUB;
            double s = 0.0;
            #pragma unroll
            for (int dd = 0; dd < DSUB; ++dd) {
                double diff = xd[dd] - (double)cp[dd];
                s = fma(diff, diff, s);
            }
            if (s < bd) { bd = s; bi = c; }
        }
        #pragma unroll
        for (int msk = 1; msk <= 32; msk <<= 1) {
            double ob = __shfl_xor(bd, msk);
            int   oi  = __shfl_xor(bi, msk);
            if (ob < bd || (ob == bd && oi < bi)) { bd = ob; bi = oi; }
        }
        if (l < DSUB) out[(size_t)n * DIMS + m * DSUB + l] = cbm[bi * DSUB + l];
    }
}

extern "C" void kernel_launch(void* const* d_in, const int* in_sizes, int n_in,
                              void* d_out, int out_size, void* d_ws, size_t ws_size,
                              hipStream_t stream)
{
    const float* embeds    = (const float*)d_in[0];
    const float* codebooks = (const float*)d_in[1];
    float* out = (float*)d_out;

    unsigned* flag_cnt  = (unsigned*)d_ws;
    unsigned* flag_list = (unsigned*)d_ws + 4;   // 16B offset
    unsigned flag_cap = 0;
    if (ws_size >= 32) {
        size_t cap = (ws_size - 16) / sizeof(unsigned);
        flag_cap = (cap > 0x7FFFFFFFull) ? 0x7FFFFFFFu : (unsigned)cap;
    }

    hipMemsetAsync(d_ws, 0, 16, stream);

    pq_main<<<dim3(1024), dim3(256), 0, stream>>>(
        embeds, codebooks, out, flag_cnt, flag_list, flag_cap);

    pq_refine<<<dim3(512), dim3(256), 0, stream>>>(
        embeds, codebooks, out, flag_cnt, flag_list, flag_cap);
}